// Round 9
// baseline (297.024 us; speedup 1.0000x reference)
//
#include <hip/hip_runtime.h>
#include <math.h>

#define S_LEN  2048
#define NH     16
#define HD     64
#define DMODEL 1024
#define BATCH  4
#define M_TOK  (BATCH * S_LEN)   // 8192

typedef __bf16 bf16x8 __attribute__((ext_vector_type(8)));
typedef float  floatx4 __attribute__((ext_vector_type(4)));
typedef float  floatx16 __attribute__((ext_vector_type(16)));

typedef __attribute__((address_space(1))) const void cg_void;
typedef __attribute__((address_space(3))) void lds_void;

#if __has_builtin(__builtin_amdgcn_exp2f)
#define EXP2(x) __builtin_amdgcn_exp2f(x)
#else
#define EXP2(x) exp2f(x)
#endif

__device__ __forceinline__ void gload16(const void* g, void* l) {
    __builtin_amdgcn_global_load_lds((cg_void*)g, (lds_void*)l, 16, 0, 0);
}

__device__ __forceinline__ unsigned short f2bf(float f) {   // RNE f32->bf16
    unsigned int u = __builtin_bit_cast(unsigned int, f);
    u = (u + 0x7FFF + ((u >> 16) & 1)) >> 16;
    return (unsigned short)u;
}

__device__ __forceinline__ unsigned cvtpk(float lo, float hi) {  // [bf16(lo) | bf16(hi)<<16]
    unsigned r;
    asm volatile("v_cvt_pk_bf16_f32 %0, %1, %2" : "=v"(r) : "v"(lo), "v"(hi));
    return r;
}

// (a,b) -> a' = [a.lo32lanes | b.lo32lanes], b' = [a.hi32lanes | b.hi32lanes]
__device__ __forceinline__ void swap32(unsigned &a, unsigned &b) {
    asm volatile("v_permlane32_swap_b32 %0, %1" : "+v"(a), "+v"(b));
}

__device__ __forceinline__ float max3f(float a, float b, float c) {
    float r;
    asm("v_max3_f32 %0, %1, %2, %3" : "=v"(r) : "v"(a), "v"(b), "v"(c));
    return r;
}

// ---------------- fused prep kernel ----------------
// sections by blockIdx.x:
//  [0, 8192)        : x fp32 -> bf16            (1024 elems/block)
//  [8192, 12288)    : 4 weight transposes fp32[K][N] -> bf16[N][K]
//  [12288, 12544)   : RoPE cos/sin table [S_LEN][32]  (fp32 math)
//  [12544]          : mask bias (fragment order)
//  [12545]          : per-batch tile-valid bitmask
__global__ __launch_bounds__(256)
void prep_kernel(const float* __restrict__ x,
                 const float* __restrict__ wq, const float* __restrict__ wk,
                 const float* __restrict__ wv, const float* __restrict__ wo,
                 const int* __restrict__ mask,
                 unsigned short* __restrict__ xb, unsigned short* __restrict__ wstack,
                 unsigned short* __restrict__ wto,
                 float* __restrict__ cs, float* __restrict__ sn,
                 float* __restrict__ biasG, unsigned* __restrict__ flagmask)
{
    __shared__ float tile[32][33];
    __shared__ unsigned fm[4];
    const int blk = blockIdx.x;
    const int tid = threadIdx.x;
    constexpr size_t WSZ = (size_t)DMODEL * DMODEL;

    if (blk < 8192) {                       // ---- convert x ----
        const int idx = blk * 256 + tid;
        float4 a = *reinterpret_cast<const float4*>(&x[(size_t)idx * 4]);
        ushort4 o;
        o.x = f2bf(a.x); o.y = f2bf(a.y); o.z = f2bf(a.z); o.w = f2bf(a.w);
        *reinterpret_cast<ushort4*>(&xb[(size_t)idx * 4]) = o;
    } else if (blk < 12288) {               // ---- weight transposes ----
        const int rel = blk - 8192;
        const int mat = rel >> 10;
        const float* w = (mat == 0) ? wq : (mat == 1) ? wk : (mat == 2) ? wv : wo;
        unsigned short* wt = (mat < 3) ? (wstack + (size_t)mat * WSZ) : wto;
        const int rel10 = rel & 1023;
        const int n0 = (rel10 & 31) * 32;
        const int k0 = (rel10 >> 5) * 32;
        const int tx  = tid & 31;
        const int ty8 = tid >> 5;
        #pragma unroll
        for (int i = 0; i < 4; ++i)
            tile[ty8 + i * 8][tx] = w[(size_t)(k0 + ty8 + i * 8) * DMODEL + n0 + tx];
        __syncthreads();
        #pragma unroll
        for (int i = 0; i < 4; ++i)
            wt[(size_t)(n0 + ty8 + i * 8) * DMODEL + k0 + tx] = f2bf(tile[tx][ty8 + i * 8]);
    } else if (blk < 12544) {               // ---- RoPE table (fp32) ----
        const int idx = (blk - 12288) * 256 + tid;
        const int j = idx & 31;
        const int s = idx >> 5;
        const float invf = exp2f(-(float)j * (13.287712379549449f / 32.0f));
        const float a = (float)s * invf;
        cs[idx] = cosf(a);
        sn[idx] = sinf(a);
    } else if (blk == 12544) {              // ---- mask bias ----
        for (int i = tid; i < BATCH * S_LEN; i += 256) {
            const int b = i >> 11, r = i & 2047;
            const int kt = r >> 6, rem = r & 63;
            const int hig = rem >> 5, kbb = (rem >> 4) & 1, reg = rem & 15;
            const int key = kt * 64 + kbb * 32 + hig * 4 + (reg & 3) + ((reg >> 2) << 3);
            biasG[i] = mask[b * S_LEN + key] ? 0.0f : -3.0e38f;
        }
    } else {                                // ---- flag bitmask ----
        if (tid < 4) fm[tid] = 0;
        __syncthreads();
        for (int i = tid; i < BATCH * 32; i += 256) {
            const int b = i >> 5, kt = i & 31;
            int ok = 1;
            for (int j = 0; j < 64; ++j) ok &= (mask[b * S_LEN + kt * 64 + j] != 0);
            if (ok) atomicOr(&fm[b], 1u << kt);
        }
        __syncthreads();
        if (tid < 4) flagmask[tid] = fm[tid];
    }
}

// ---------------- fused QKV GEMM + RoPE epilogue (deep pipeline) ----------------
// A: xb [8192][1024] bf16.  Bt: wq|wk|wv transposed stack [3072][1024] bf16.
// sect: 0 -> qbf [bh][s][pair-interleaved 64] (pre-scaled 0.125*log2e, RoPE'd)
//       1 -> kbf [bh][s][pair-interleaved 64] (RoPE'd)
//       2 -> vtb [bh][d][s]
// q/k row layout: element 2*d + (orig_d>=32), d = orig_d & 31. Same permutation
// for q and k => QK^T dot product unchanged; attn reads rows verbatim.
__global__ __launch_bounds__(256, 2)
void gemm_qkv(const unsigned short* __restrict__ A, const unsigned short* __restrict__ Bt,
              const float* __restrict__ bq, const float* __restrict__ bk,
              const float* __restrict__ bv,
              const float* __restrict__ cs, const float* __restrict__ sn,
              unsigned short* __restrict__ qbf, unsigned short* __restrict__ kbf,
              unsigned short* __restrict__ vtb)
{
    constexpr int K = DMODEL;
    __shared__ unsigned short As[4][128 * 32];   // 32 KB
    __shared__ unsigned short Bs[4][128 * 32];   // 32 KB

    const int tid  = threadIdx.x;
    const int lane = tid & 63;
    const int w    = tid >> 6;
    const int wm   = w >> 1;
    const int wn   = w & 1;

    // XCD-bijective swizzle: nwg = 24*64 = 1536, 1536%8==0
    const int gx   = gridDim.x;                 // 24
    int lin = blockIdx.y * gx + blockIdx.x;
    const int cpx = (gx * gridDim.y) >> 3;
    lin = (lin & 7) * cpx + (lin >> 3);
    const int row0 = (lin / gx) * 128;
    const int col0 = (lin % gx) * 128;          // 0..2944

    const int sr  = lane >> 2;
    const int sk8 = (lane & 3) * 8;
    const int fr  = lane & 15;
    const int fk  = (lane >> 4) * 8;

    floatx4 acc[4][4] = {};

    #define GSTAGE(KT, BUF) do {                                                            \
        const int k0_ = (KT) * 32;                                                          \
        _Pragma("unroll")                                                                   \
        for (int t = 0; t < 2; ++t) {                                                       \
            const int chunk = w * 32 + t * 16;                                              \
            gload16(A  + (size_t)(row0 + chunk + sr) * K + k0_ + sk8, &As[BUF][chunk * 32]);\
            gload16(Bt + (size_t)(col0 + chunk + sr) * K + k0_ + sk8, &Bs[BUF][chunk * 32]);\
        }                                                                                   \
    } while (0)

    auto COMPUTE = [&](int buf) {
        bf16x8 av[4], bv4[4];
        #pragma unroll
        for (int m = 0; m < 4; ++m)
            av[m] = *reinterpret_cast<const bf16x8*>(&As[buf][(wm * 64 + m * 16 + fr) * 32 + fk]);
        #pragma unroll
        for (int n = 0; n < 4; ++n)
            bv4[n] = *reinterpret_cast<const bf16x8*>(&Bs[buf][(wn * 64 + n * 16 + fr) * 32 + fk]);
        __builtin_amdgcn_s_setprio(1);
        #pragma unroll
        for (int m = 0; m < 4; ++m)
            #pragma unroll
            for (int n = 0; n < 4; ++n)
                acc[m][n] = __builtin_amdgcn_mfma_f32_16x16x32_bf16(av[m], bv4[n], acc[m][n], 0, 0, 0);
        __builtin_amdgcn_s_setprio(0);
    };

    GSTAGE(0, 0);
    GSTAGE(1, 1);
    for (int kt = 0; kt < 30; ++kt) {
        GSTAGE(kt + 2, (kt + 2) & 3);
        asm volatile("s_waitcnt vmcnt(8)" ::: "memory");
        __builtin_amdgcn_s_barrier();
        __builtin_amdgcn_sched_barrier(0);
        COMPUTE(kt & 3);
    }
    asm volatile("s_waitcnt vmcnt(4)" ::: "memory");
    __builtin_amdgcn_s_barrier();
    __builtin_amdgcn_sched_barrier(0);
    COMPUTE(2);
    asm volatile("s_waitcnt vmcnt(0)" ::: "memory");
    __builtin_amdgcn_s_barrier();
    __builtin_amdgcn_sched_barrier(0);
    COMPUTE(3);
    #undef GSTAGE

    const int rbase = lane >> 4;
    const int sect  = col0 >> 10;        // uniform per block
    const int c0    = col0 & 1023;

    if (sect == 2) {
        #pragma unroll
        for (int m = 0; m < 4; ++m)
            #pragma unroll
            for (int n = 0; n < 4; ++n) {
                const int c  = c0 + wn * 64 + n * 16 + fr;
                const int hh = c >> 6, d = c & 63;
                const int mr0 = row0 + wm * 64 + m * 16 + rbase * 4;
                const int bb = mr0 >> 11, ss = mr0 & (S_LEN - 1);
                const float bc = bv[c];
                ushort4 pk4;
                pk4.x = f2bf(acc[m][n][0] + bc);
                pk4.y = f2bf(acc[m][n][1] + bc);
                pk4.z = f2bf(acc[m][n][2] + bc);
                pk4.w = f2bf(acc[m][n][3] + bc);
                *reinterpret_cast<ushort4*>(
                    &vtb[((size_t)(bb * NH + hh) * HD + d) * S_LEN + ss]) = pk4;
            }
    } else {
        unsigned short* outp = sect ? kbf : qbf;
        const float* bias = sect ? bk : bq;
        const float sc = sect ? 1.0f : 0.125f * 1.44269504088896f;  // fold log2e into Q
        #pragma unroll
        for (int m = 0; m < 4; ++m)
            #pragma unroll
            for (int n = 0; n < 2; ++n) {       // (d, d+32) pair lives in (n, n+2)
                const int c  = c0 + wn * 64 + n * 16 + fr;
                const int hh = c >> 6, dd = c & 63;     // dd < 32
                const float b1 = bias[c], b2 = bias[c + 32];
                #pragma unroll
                for (int r = 0; r < 4; ++r) {
                    const int mr = row0 + wm * 64 + m * 16 + rbase * 4 + r;
                    const int bb = mr >> 11, ss = mr & (S_LEN - 1);
                    const float v1 = acc[m][n][r] + b1;
                    const float v2 = acc[m][n + 2][r] + b2;
                    const float co = cs[ss * 32 + dd];
                    const float si = sn[ss * 32 + dd];
                    ushort2 st;
                    st.x = f2bf((v1 * co - v2 * si) * sc);
                    st.y = f2bf((v2 * co + v1 * si) * sc);
                    *reinterpret_cast<ushort2*>(
                        &outp[((size_t)(bb * NH + hh) * S_LEN + ss) * HD + 2 * dd]) = st;
                }
            }
    }
}

// ---------------- swapped-QK^T MFMA flash attention, deep pipeline ----------------
// 8 waves x 32 q-rows = 256 q-rows/block; 4 LDS buffers, 2-tile-deep prefetch,
// raw s_barrier + counted vmcnt (never 0 in main loop).
// launch_bounds(512, 4): LDS (64KB) limits to 2 blocks/CU = 4 waves/EU anyway,
// so allow 128 VGPR — live state (qf 16 + oacc 32 + sacc 32 + addrs) exceeds
// the default 64-VGPR cap, which forced spills/remat (r7: VGPR=64, VALUBusy 62%).
__global__ __launch_bounds__(512, 4)
void attn_mfma3(const unsigned short* __restrict__ qbf,
                const unsigned short* __restrict__ kbf,
                const unsigned short* __restrict__ vtb,
                const float* __restrict__ biasG,
                const unsigned* __restrict__ flagmask,
                unsigned short* __restrict__ ctxb)
{
    __shared__ unsigned short Ks[4][64 * 64];   // [key][d], xor-swizzled via source
    __shared__ unsigned short Vs[4][64 * 64];   // [d][key], xor-swizzled via source

    const int tid  = threadIdx.x;
    const int lane = tid & 63;
    const int w    = tid >> 6;                  // 0..7
    const int bh   = blockIdx.x;
    const int b    = bh >> 4;
    const int h    = bh & 15;
    const int q0   = blockIdx.y * 256 + w * 32;
    const size_t hb = (size_t)bh * S_LEN * HD;

    const int lo5 = lane & 31;
    const int hi5 = lane >> 5;
    const int srow   = lane >> 3;                // 0..7
    const int schunk = (lane & 7) ^ srow;        // pre-swizzled source chunk
    const unsigned fl = flagmask[b];

    // Q as MFMA-B fragments (pair-interleaved layout; same permutation as K)
    bf16x8 qf[4];
    #pragma unroll
    for (int ks = 0; ks < 4; ++ks)
        qf[ks] = *reinterpret_cast<const bf16x8*>(
            &qbf[hb + (size_t)(q0 + lo5) * HD + ks * 16 + hi5 * 8]);

    floatx16 oacc[2];
    #pragma unroll
    for (int v = 0; v < 2; ++v)
        #pragma unroll
        for (int i = 0; i < 16; ++i) oacc[v][i] = 0.0f;
    float mrow = -3.0e38f, lrow = 0.0f;

    // per wave: 1 K-gload + 1 V-gload per tile (8 rows each)
    #define STAGE(KT, BUF) do {                                                             \
        const int r0_ = w * 8;                                                              \
        gload16(kbf + hb + (size_t)((KT) * 64 + r0_ + srow) * HD + schunk * 8,              \
                &Ks[BUF][r0_ * 64]);                                                        \
        gload16(vtb + ((size_t)bh * HD + r0_ + srow) * S_LEN + (KT) * 64 + schunk * 8,      \
                &Vs[BUF][r0_ * 64]);                                                        \
    } while (0)

    auto TILE = [&](int kt, int buf) {
        // ---- S^T = K.Q^T (+ mask bias C-init when tile has invalid keys) ----
        floatx16 sacc[2];
        if ((fl >> kt) & 1u) {
            #pragma unroll
            for (int kb = 0; kb < 2; ++kb)
                #pragma unroll
                for (int i = 0; i < 16; ++i) sacc[kb][i] = 0.0f;
        } else {
            const float4* bp = reinterpret_cast<const float4*>(
                &biasG[(size_t)(b * 32 + kt) * 64 + hi5 * 32]);
            #pragma unroll
            for (int kb = 0; kb < 2; ++kb)
                #pragma unroll
                for (int t = 0; t < 4; ++t) {
                    const float4 b4 = bp[kb * 4 + t];
                    sacc[kb][t * 4 + 0] = b4.x; sacc[kb][t * 4 + 1] = b4.y;
                    sacc[kb][t * 4 + 2] = b4.z; sacc[kb][t * 4 + 3] = b4.w;
                }
        }

        __builtin_amdgcn_s_setprio(1);
        #pragma unroll
        for (int kb = 0; kb < 2; ++kb) {
            #pragma unroll
            for (int ks = 0; ks < 4; ++ks) {
                const bf16x8 ak = *reinterpret_cast<const bf16x8*>(
                    (const char*)&Ks[buf][0] + (kb * 32 + lo5) * 128 +
                    ((ks * 32 + hi5 * 16) ^ ((lo5 & 7) << 4)));
                sacc[kb] = __builtin_amdgcn_mfma_f32_32x32x16_bf16(ak, qf[ks], sacc[kb], 0, 0, 0);
            }
        }
        __builtin_amdgcn_s_setprio(0);

        // ---- log2-domain online softmax with defer-max (THR=8) ----
        float r0 = max3f(sacc[0][0],  sacc[0][1],  sacc[0][2]);
        float r1 = max3f(sacc[0][3],  sacc[0][4],  sacc[0][5]);
        float r2 = max3f(sacc[0][6],  sacc[0][7],  sacc[0][8]);
        float r3 = max3f(sacc[0][9],  sacc[0][10], sacc[0][11]);
        float r4 = max3f(sacc[0][12], sacc[0][13], sacc[0][14]);
        float r5 = max3f(sacc[1][0],  sacc[1][1],  sacc[1][2]);
        float r6 = max3f(sacc[1][3],  sacc[1][4],  sacc[1][5]);
        float r7 = max3f(sacc[1][6],  sacc[1][7],  sacc[1][8]);
        float r8 = max3f(sacc[1][9],  sacc[1][10], sacc[1][11]);
        float r9 = max3f(sacc[1][12], sacc[1][13], sacc[1][14]);
        float s1 = max3f(r0, r1, r2);
        float s2 = max3f(r3, r4, r5);
        float s3 = max3f(r6, r7, r8);
        float s4 = max3f(r9, sacc[0][15], sacc[1][15]);
        float pmax = fmaxf(max3f(s1, s2, s3), s4);
        pmax = fmaxf(pmax, __shfl_xor(pmax, 32));

        if (!__all(pmax <= mrow + 8.0f)) {     // rescale path (rare)
            const float mnew = fmaxf(mrow, pmax);
            const float fscale = EXP2(mrow - mnew);
            mrow = mnew;
            lrow *= fscale;
            #pragma unroll
            for (int v = 0; v < 2; ++v)
                #pragma unroll
                for (int i = 0; i < 16; ++i) oacc[v][i] *= fscale;
        }

        float rs0 = 0.0f, rs1 = 0.0f, rs2 = 0.0f, rs3 = 0.0f;
        #pragma unroll
        for (int kb = 0; kb < 2; ++kb)
            #pragma unroll
            for (int i = 0; i < 16; i += 4) {
                float p0 = EXP2(sacc[kb][i + 0] - mrow);
                float p1 = EXP2(sacc[kb][i + 1] - mrow);
                float p2 = EXP2(sacc[kb][i + 2] - mrow);
                float p3 = EXP2(sacc[kb][i + 3] - mrow);
                sacc[kb][i + 0] = p0; sacc[kb][i + 1] = p1;
                sacc[kb][i + 2] = p2; sacc[kb][i + 3] = p3;
                rs0 += p0; rs1 += p1; rs2 += p2; rs3 += p3;
            }
        float rs = (rs0 + rs1) + (rs2 + rs3);
        rs += __shfl_xor(rs, 32);
        lrow += rs;

        // ---- P -> bf16 PV B-fragments entirely in-register ----
        unsigned U0[8], U1[8];
        #pragma unroll
        for (int kb = 0; kb < 2; ++kb)
            #pragma unroll
            for (int s = 0; s < 4; ++s) {
                U0[kb * 4 + s] = cvtpk(sacc[kb][4 * s + 0], sacc[kb][4 * s + 1]);
                U1[kb * 4 + s] = cvtpk(sacc[kb][4 * s + 2], sacc[kb][4 * s + 3]);
            }
        union PF { unsigned u[4]; bf16x8 v; };
        PF pf[4];
        #pragma unroll
        for (int ks = 0; ks < 4; ++ks) {
            unsigned a0 = U0[2 * ks], b0 = U0[2 * ks + 1];
            swap32(a0, b0);
            unsigned a1 = U1[2 * ks], b1 = U1[2 * ks + 1];
            swap32(a1, b1);
            pf[ks].u[0] = a0; pf[ks].u[1] = a1;
            pf[ks].u[2] = b0; pf[ks].u[3] = b1;
        }

        // ---- O^T += V^T . P^T ----
        __builtin_amdgcn_s_setprio(1);
        #pragma unroll
        for (int vb = 0; vb < 2; ++vb) {
            #pragma unroll
            for (int ks = 0; ks < 4; ++ks) {
                const bf16x8 av = *reinterpret_cast<const bf16x8*>(
                    (const char*)&Vs[buf][0] + (vb * 32 + lo5) * 128 +
                    ((ks * 32 + hi5 * 16) ^ ((lo5 & 7) << 4)));
                oacc[vb] = __builtin_amdgcn_mfma_f32_32x32x16_bf16(av, pf[ks].v, oacc[vb], 0, 0, 0);
            }
        }
        __builtin_amdgcn_s_setprio(0);
    };

    // ---- prologue: 2 tiles in flight ----
    STAGE(0, 0);
    STAGE(1, 1);

    // ---- main loop: counted vmcnt, never 0 (tiles 0..29) ----
    for (int kt = 0; kt < 30; ++kt) {
        STAGE(kt + 2, (kt + 2) & 3);
        asm volatile("s_waitcnt vmcnt(4)" ::: "memory");  // this tile's 2 loads done
        __builtin_amdgcn_s_barrier();
        __builtin_amdgcn_sched_barrier(0);
        TILE(kt, kt & 3);
    }
    // ---- epilogue tiles ----
    asm volatile("s_waitcnt vmcnt(2)" ::: "memory");
    __builtin_amdgcn_s_barrier();
    __builtin_amdgcn_sched_barrier(0);
    TILE(30, 30 & 3);
    asm volatile("s_waitcnt vmcnt(0)" ::: "memory");
    __builtin_amdgcn_s_barrier();
    __builtin_amdgcn_sched_barrier(0);
    TILE(31, 31 & 3);

    // ---- epilogue: lane writes its q-row, d = 32vb + 8s + 4hi5 + t ----
    const float inv = 1.0f / lrow;
    unsigned short* dst = &ctxb[((size_t)b * S_LEN + q0 + lo5) * DMODEL + h * HD];
    #pragma unroll
    for (int vb = 0; vb < 2; ++vb)
        #pragma unroll
        for (int s = 0; s < 4; ++s) {
            const int d0 = vb * 32 + s * 8 + hi5 * 4;
            ushort4 o4;
            o4.x = f2bf(oacc[vb][4 * s + 0] * inv);
            o4.y = f2bf(oacc[vb][4 * s + 1] * inv);
            o4.z = f2bf(oacc[vb][4 * s + 2] * inv);
            o4.w = f2bf(oacc[vb][4 * s + 3] * inv);
            *reinterpret_cast<ushort4*>(&dst[d0]) = o4;
        }
    #undef STAGE
}

// ---------------- output projection: out = (ctxb @ wto^T + bo) * mask (deep pipeline) ----------------
__global__ __launch_bounds__(256, 2)
void gemm_out(const unsigned short* __restrict__ A, const unsigned short* __restrict__ Bt,
              const float* __restrict__ bias, const int* __restrict__ mask,
              float* __restrict__ C)
{
    constexpr int K = DMODEL;
    __shared__ unsigned short As[4][128 * 32];
    __shared__ unsigned short Bs[4][128 * 32];

    const int tid  = threadIdx.x;
    const int lane = tid & 63;
    const int w    = tid >> 6;
    const int wm   = w >> 1;
    const int wn   = w & 1;

    // XCD-bijective swizzle: nwg = 8*64 = 512, 512%8==0
    const int gx   = gridDim.x;                 // 8
    int lin = blockIdx.y * gx + blockIdx.x;
    const int cpx = (gx * gridDim.y) >> 3;
    lin = (lin & 7) * cpx + (lin >> 3);
    const int row0 = (lin >> 3) * 128;          // lin / 8
    const int col0 = (lin & 7) * 128;

    const int sr  = lane >> 2;
    const int sk8 = (lane & 3) * 8;
    const int fr  = lane & 15;
    const int fk  = (lane >> 4) * 8;

    floatx4 acc[4][4] = {};

    #define GSTAGE(KT, BUF) do {                                                            \
        const int k0_ = (KT) * 32;                                                          \
        _Pragma("unroll")                                                                   \
        for (int t = 0; t < 2; ++t) {                                                       \
            const int chunk = w * 32 + t * 16;                                              \
            gload16(A  + (size_t)(row0 + chunk + sr) * K + k0_ + sk8, &As[BUF][chunk * 32]);\
            gload16(Bt + (size_t)(col0 + chunk + sr) * K + k0_ + sk8, &Bs[BUF][chunk * 32]);\
        }                                                                                   \
    } while (0)

    auto COMPUTE = [&](int buf) {
        bf16x8 av[4], bv4[4];
        #pragma unroll
        for (int m = 0; m < 4; ++m)
            av[m] = *reinterpret_cast<const bf16x8*>(&As[buf][(wm * 64 + m * 16 + fr) * 32 + fk]);
        #pragma unroll
        for (int n = 0; n < 4; ++n)
            bv4[n] = *reinterpret_cast<const bf16x8*>(&Bs[buf][(wn * 64 + n * 16 + fr) * 32 + fk]);
        __builtin_amdgcn_s_setprio(1);
        #pragma unroll
        for (int m = 0; m < 4; ++m)
            #pragma unroll
            for (int n = 0; n < 4; ++n)
                acc[m][n] = __builtin_amdgcn_mfma_f32_16x16x32_bf16(av[m], bv4[n], acc[m][n], 0, 0, 0);
        __builtin_amdgcn_s_setprio(0);
    };

    GSTAGE(0, 0);
    GSTAGE(1, 1);
    for (int kt = 0; kt < 30; ++kt) {
        GSTAGE(kt + 2, (kt + 2) & 3);
        asm volatile("s_waitcnt vmcnt(8)" ::: "memory");
        __builtin_amdgcn_s_barrier();
        __builtin_amdgcn_sched_barrier(0);
        COMPUTE(kt & 3);
    }
    asm volatile("s_waitcnt vmcnt(4)" ::: "memory");
    __builtin_amdgcn_s_barrier();
    __builtin_amdgcn_sched_barrier(0);
    COMPUTE(2);
    asm volatile("s_waitcnt vmcnt(0)" ::: "memory");
    __builtin_amdgcn_s_barrier();
    __builtin_amdgcn_sched_barrier(0);
    COMPUTE(3);
    #undef GSTAGE

    const int rbase = lane >> 4;
    #pragma unroll
    for (int m = 0; m < 4; ++m)
        #pragma unroll
        for (int n = 0; n < 4; ++n) {
            const int c = col0 + wn * 64 + n * 16 + fr;
            const float bc = bias[c];
            #pragma unroll
            for (int r = 0; r < 4; ++r) {
                const int mr = row0 + wm * 64 + m * 16 + rbase * 4 + r;
                C[(size_t)mr * DMODEL + c] = mask[mr] ? (acc[m][n][r] + bc) : 0.0f;
            }
        }
}

extern "C" void kernel_launch(void* const* d_in, const int* in_sizes, int n_in,
                              void* d_out, int out_size, void* d_ws, size_t ws_size,
                              hipStream_t stream) {
    const float* x    = (const float*)d_in[0];
    const int*   mask = (const int*)d_in[1];
    const float* wq = (const float*)d_in[2];
    const float* bq = (const float*)d_in[3];
    const float* wk = (const float*)d_in[4];
    const float* bk = (const float*)d_in[5];
    const float* wv = (const float*)d_in[6];
    const float* bv = (const float*)d_in[7];
    const float* wo = (const float*)d_in[8];
    const float* bo = (const float*)d_in[9];
    float* out = (float*)d_out;

    const size_t QKV = (size_t)M_TOK * DMODEL;     // 8388608
    const size_t WSZ = (size_t)DMODEL * DMODEL;    // 1048576
    unsigned short* xb     = (unsigned short*)d_ws;
    unsigned short* wstack = xb + QKV;             // wq^T | wk^T | wv^T contiguous
    unsigned short* wto    = wstack + 3 * WSZ;
    unsigned short* qbf    = wto + WSZ;
    unsigned short* kbf    = qbf + QKV;
    unsigned short* vtb    = kbf + QKV;
    unsigned short* ctxb   = vtb + QKV;
    float* cs    = (float*)(ctxb + QKV);
    float* sn    = cs + (size_t)S_LEN * 32;
    float* biasG = sn + (size_t)S_LEN * 32;        // [4][2048] fragment-ordered
    unsigned* flagmask = (unsigned*)(biasG + (size_t)BATCH * S_LEN);   // [4] bitmasks
    // total ~90 MB

    prep_kernel<<<12546, 256, 0, stream>>>(x, wq, wk, wv, wo, mask,
                                           xb, wstack, wto, cs, sn, biasG, flagmask);

    dim3 qkvgrid(3 * DMODEL / 128, M_TOK / 128);   // (24, 64)
    gemm_qkv<<<qkvgrid, 256, 0, stream>>>(xb, wstack, bq, bk, bv, cs, sn, qbf, kbf, vtb);

    dim3 agrid(BATCH * NH, S_LEN / 256);           // (64 heads, 8 qblocks)
    attn_mfma3<<<agrid, 512, 0, stream>>>(qbf, kbf, vtb, biasG, flagmask, ctxb);

    dim3 ogrid(DMODEL / 128, M_TOK / 128);         // (8, 64)
    gemm_out<<<ogrid, 256, 0, stream>>>(ctxb, wto, bo, mask, out);
}